// Round 2
// 475.754 us; speedup vs baseline: 1.0197x; 1.0197x over previous
//
#include <hip/hip_runtime.h>

#define EPS 1e-5f
#define NDOM 8
#define NB 64
#define NC 256
#define NH 32
#define NW 128
#define HW (NH * NW)

// Native 4-float vector type usable with __builtin_nontemporal_store.
typedef float vfloat4 __attribute__((ext_vector_type(4)));

// Workspace layout (all regions fully overwritten each launch -> poison-safe):
//   partial      : float2[NB*NC]    per-(b,c) row (sum, sumsq)
//   scale_shift  : float2[NDOM*NC]  per-(domain,c) (scale, shift)

// Kernel 1: per-(b,c) spatial sum/sumsq -> partial[bc]. No atomics, no memset.
__global__ __launch_bounds__(256) void row_stats(
    const float* __restrict__ x, float2* __restrict__ partial) {
    const int bc = blockIdx.x;                     // 0 .. NB*NC-1
    const vfloat4* xp = (const vfloat4*)(x + (size_t)bc * HW);

    float s = 0.f, sq = 0.f;
    // HW/4 = 1024 float4; 256 threads -> 4 each, coalesced.
#pragma unroll
    for (int k = 0; k < 4; ++k) {
        vfloat4 v = xp[threadIdx.x + k * 256];
        s  += v.x + v.y + v.z + v.w;
        sq += v.x * v.x + v.y * v.y + v.z * v.z + v.w * v.w;
    }
    // wave64 shuffle reduction
    for (int off = 32; off > 0; off >>= 1) {
        s  += __shfl_down(s, off, 64);
        sq += __shfl_down(sq, off, 64);
    }
    __shared__ float ls[4], lsq[4];
    const int lane = threadIdx.x & 63;
    const int wave = threadIdx.x >> 6;
    if (lane == 0) { ls[wave] = s; lsq[wave] = sq; }
    __syncthreads();
    if (threadIdx.x == 0) {
        partial[bc] = make_float2(ls[0] + ls[1] + ls[2] + ls[3],
                                  lsq[0] + lsq[1] + lsq[2] + lsq[3]);
    }
}

// Kernel 2 (tiny): reduce partials over samples of each domain, emit
// per-(domain, channel) scale/shift. Grid: NDOM blocks x NC threads.
__global__ __launch_bounds__(NC) void finalize_stats(
    const float2* __restrict__ partial, const int* __restrict__ dom,
    const float* __restrict__ wgt, const float* __restrict__ bia,
    float2* __restrict__ scale_shift) {
    const int d = blockIdx.x;      // 0..NDOM-1
    const int c = threadIdx.x;     // 0..NC-1

    float S = 0.f, SQ = 0.f;
    int n = 0;
    for (int b = 0; b < NB; ++b) {
        if (dom[b] - 1 == d) {                 // dom[] is uniform -> scalar load
            float2 p = partial[b * NC + c];    // coalesced across threads
            S += p.x;
            SQ += p.y;
            ++n;
        }
    }
    const float cnt   = fmaxf((float)n * (float)HW, 1.0f);
    const float mean  = S / cnt;
    const float var   = SQ / cnt - mean * mean;
    const float inv   = rsqrtf(var + EPS);
    const float scale = wgt[c] * inv;
    scale_shift[d * NC + c] = make_float2(scale, bia[c] - mean * scale);
}

// Kernel 3: normalize. Reverse block order (hottest x rows still in L3),
// non-temporal stores so out doesn't evict x from the Infinity Cache.
__global__ __launch_bounds__(256) void norm_kernel(
    const float* __restrict__ x, const int* __restrict__ dom,
    const float2* __restrict__ scale_shift, float* __restrict__ out) {
    const int bc = NB * NC - 1 - blockIdx.x;   // reverse order
    const int b = bc / NC;
    const int c = bc % NC;

    const int d = dom[b] - 1;                  // uniform -> scalar load
    const float2 ss = scale_shift[d * NC + c]; // uniform -> scalar load
    const float scale = ss.x;
    const float shift = ss.y;

    const vfloat4* xp = (const vfloat4*)(x + (size_t)bc * HW);
    vfloat4*       op = (vfloat4*)(out + (size_t)bc * HW);
#pragma unroll
    for (int k = 0; k < 4; ++k) {
        const int i = threadIdx.x + k * 256;
        vfloat4 v = xp[i];
        v.x = v.x * scale + shift;
        v.y = v.y * scale + shift;
        v.z = v.z * scale + shift;
        v.w = v.w * scale + shift;
        __builtin_nontemporal_store(v, &op[i]);
    }
}

extern "C" void kernel_launch(void* const* d_in, const int* in_sizes, int n_in,
                              void* d_out, int out_size, void* d_ws, size_t ws_size,
                              hipStream_t stream) {
    const float* x   = (const float*)d_in[0];
    const float* wgt = (const float*)d_in[1];
    const float* bia = (const float*)d_in[2];
    const int*   dom = (const int*)d_in[3];
    float* out = (float*)d_out;

    float2* partial     = (float2*)d_ws;             // [NB*NC]
    float2* scale_shift = partial + NB * NC;         // [NDOM*NC]

    row_stats<<<NB * NC, 256, 0, stream>>>(x, partial);
    finalize_stats<<<NDOM, NC, 0, stream>>>(partial, dom, wgt, bia, scale_shift);
    norm_kernel<<<NB * NC, 256, 0, stream>>>(x, dom, scale_shift, out);
}